// Round 8
// baseline (36171.045 us; speedup 1.0000x reference)
//
#include <hip/hip_runtime.h>

typedef unsigned short u16;
typedef unsigned int u32;
typedef unsigned long long u64;
typedef __attribute__((ext_vector_type(8))) short bf16x8;
typedef __attribute__((ext_vector_type(4))) float f32x4;
typedef __attribute__((ext_vector_type(4))) _Float16 f16x4;

#define MFMA16(a, b, c) __builtin_amdgcn_mfma_f32_16x16x32_bf16((a), (b), (c), 0, 0, 0)

__device__ __forceinline__ u16 f2bf(float f) {
    union { float f; u32 u; } v; v.f = f;
    u32 r = v.u + 0x7FFFu + ((v.u >> 16) & 1u);
    return (u16)(r >> 16);
}
__device__ __forceinline__ float sigmoidf_(float x) {
    return 1.0f / (1.0f + __expf(-x));
}
__device__ __forceinline__ float tanhf_(float x) {
    float e = __expf(-2.0f * x);
    return (1.0f - e) / (1.0f + e);
}

// ---------------- mask: mask[row] = any(X[row, :512] != 0) ----------------
__global__ void mask_kernel(const float* __restrict__ X, int* __restrict__ mask) {
    int row = blockIdx.x;
    int lane = threadIdx.x;
    const float* r = X + (size_t)row * 512;
    int nz = 0;
    #pragma unroll
    for (int i = 0; i < 8; ++i) nz |= (r[lane + 64 * i] != 0.0f);
    nz = __any(nz);
    if (lane == 0) mask[row] = nz ? 1 : 0;
}

// ---------------- cast fp32 -> bf16 (4 elems/thread) ----------------
__global__ void cast_bf16_kernel(const float* __restrict__ in, u16* __restrict__ out, int n) {
    int i = (blockIdx.x * blockDim.x + threadIdx.x) * 4;
    if (i + 3 < n) {
        float4 v = *(const float4*)(in + i);
        u32 a = (u32)f2bf(v.x) | ((u32)f2bf(v.y) << 16);
        u32 b = (u32)f2bf(v.z) | ((u32)f2bf(v.w) << 16);
        *(uint2*)(out + i) = make_uint2(a, b);
    }
}

// ---------------- transpose + cast: in fp32 [K][N] -> out bf16 [N][K] ----------------
__global__ void transpose_cast_kernel(const float* __restrict__ in, u16* __restrict__ out,
                                      int K, int N) {
    __shared__ float tile[32][33];
    int k0 = blockIdx.y * 32, n0 = blockIdx.x * 32;
    int tx = threadIdx.x, ty = threadIdx.y;
    #pragma unroll
    for (int i = ty; i < 32; i += 8)
        tile[i][tx] = in[(size_t)(k0 + i) * N + (n0 + tx)];
    __syncthreads();
    #pragma unroll
    for (int i = ty; i < 32; i += 8)
        out[(size_t)(n0 + i) * K + (k0 + tx)] = f2bf(tile[tx][i]);
}

// ---------------- GEMM: xz = A @ Bt^T + bias, gate-fused n-tiling (R16) ----------
// C element index: (((t*32 + slice)*64 + b)*16 + dcol)*4 + g, slice = sl*2 + half.
__global__ __launch_bounds__(256) void gemm_xz_kernel(
        const u16* __restrict__ A, const u16* __restrict__ Bt,
        const float* __restrict__ bias, _Float16* __restrict__ C, int K) {
    int w = threadIdx.x >> 6, lane = threadIdx.x & 63;
    int q = lane >> 4, col = lane & 15;
    int m0 = blockIdx.x * 256 + w * 64;   // wave's 64 rows (4 m-frags of 16)
    int sl = blockIdx.y;                  // double-slice 0..15 (dcols sl*32..+31)

    const u16* arow = A + (size_t)(m0 + col) * K + q * 8;        // + mf*16*K
    const u16* brow = Bt + (size_t)(sl * 32 + col) * K + q * 8;  // + (half*16+g*512)*K

    f32x4 acc[4][8];   // [mf][half*4+g]
    #pragma unroll
    for (int mf = 0; mf < 4; ++mf)
        #pragma unroll
        for (int j = 0; j < 8; ++j) acc[mf][j] = (f32x4){0.f, 0.f, 0.f, 0.f};

    #pragma unroll 1
    for (int kc = 0; kc < K; kc += 32) {
        bf16x8 b[8], a[4];
        #pragma unroll
        for (int j = 0; j < 8; ++j) {
            int g = j & 3, half = j >> 2;
            b[j] = *(const bf16x8*)(brow + (size_t)(g * 512 + half * 16) * K + kc);
        }
        #pragma unroll
        for (int mf = 0; mf < 4; ++mf)
            a[mf] = *(const bf16x8*)(arow + (size_t)mf * 16 * K + kc);
        #pragma unroll
        for (int mf = 0; mf < 4; ++mf)
            #pragma unroll
            for (int j = 0; j < 8; ++j)
                acc[mf][j] = MFMA16(a[mf], b[j], acc[mf][j]);
    }

    float bs[8];
    #pragma unroll
    for (int j = 0; j < 8; ++j) {
        int g = j & 3, half = j >> 2;
        bs[j] = bias[g * 512 + sl * 32 + half * 16 + col];
    }

    #pragma unroll
    for (int mf = 0; mf < 4; ++mf) {
        #pragma unroll
        for (int r = 0; r < 4; ++r) {
            int row = m0 + mf * 16 + q * 4 + r;
            int b = row >> 8, t = row & 255;
            #pragma unroll
            for (int half = 0; half < 2; ++half) {
                union { _Float16 h[4]; u64 u; } pk;
                #pragma unroll
                for (int g = 0; g < 4; ++g)
                    pk.h[g] = (_Float16)(acc[mf][half * 4 + g][r] + bs[half * 4 + g]);
                size_t uidx = (((size_t)t * 32 + (sl * 2 + half)) * 64 + b) * 16 + col;
                ((u64*)C)[uidx] = pk.u;
            }
        }
    }
}

// ---------------- batch-sliced LSTM recurrence, v13: ZERO inter-block comm ---------
// R17: dual decomposition. Block owns 16 BATCH ROWS and computes all 2048 gate
// dims for them; h^{t+1} for its rows is produced entirely in-block, so there is
// NO exchange, NO flags, NO fabric round-trips — just one __syncthreads per step
// around an LDS h double-buffer. U (2 MB/dir) streams from L2 every step
// (~1.6 TB/s per XCD, under the ~4.3 TB/s ceiling; one block per XCD).
// grid (4 row-groups, 2 dirs) x 512 thr (8 waves). Wave w covers d in
// [w*64, w*64+64) x 4 gates = 16 n-frags (j = g*4+df, d = w*64+df*16+col).
// Per step per wave: 16 LDS A-frag reads, 256 B loads, 256 MFMAs, 16 gate-quads.
// Fragment mappings identical to gemm_xz (A: row=l&15, k=(l>>4)*8; C: col=l&15,
// row=(l>>4)*4+r). Gate math / mask semantics / xz / y / hc indexing = rec11.
// LDS h layout [2][16][520] (+8 pad: rows land 4 banks apart -> 2-way = free).
__global__ __launch_bounds__(512) void lstm_rec13_kernel(
        const _Float16* __restrict__ xz_f, const _Float16* __restrict__ xz_b,
        const u16* __restrict__ Ut_f, const u16* __restrict__ Ut_b,
        const int* __restrict__ mask,
        u16* __restrict__ y_bf,     // layer1 out (null for layer2)
        float* __restrict__ y_f32,  // layer2 H out (null for layer1)
        float* __restrict__ hc_out) // layer2 hidden @0, cell @65536 floats (null for l1)
{
    const int T = 256;
    int dir = blockIdx.y;
    int b0 = blockIdx.x * 16;
    int tid = threadIdx.x;
    int lane = tid & 63, q = lane >> 4, col = lane & 15;
    int w = __builtin_amdgcn_readfirstlane(tid >> 6);  // wave 0..7 (uniform)

    const _Float16* xz = dir ? xz_b : xz_f;
    const u16* Ut = dir ? Ut_b : Ut_f;

    // wave-uniform B base per n-frag j (g=j>>2, df=j&3): n0 = g*512 + w*64 + df*16
    const u16* bq[16];
    #pragma unroll
    for (int j = 0; j < 16; ++j) {
        int g = j >> 2, df = j & 3;
        bq[j] = Ut + (size_t)(g * 512 + w * 64 + df * 16) * 512;
    }
    int boff = col * 512 + q * 8;   // lane offset (elems); +kc*32 per k-chunk

    alignas(16) __shared__ u16 hlds[2][16][520];
    for (int i = tid; i < 2080; i += 512)        // zero buf 0 (16*520 u16)
        ((u64*)&hlds[0][0][0])[i] = 0ull;

    float creg[4][4] = {{0.f}}, hreg[4][4] = {{0.f}};   // [df][r]
    __syncthreads();

    int p = 0;
    for (int it = 0; it < T; ++it) {
        int t = dir ? (T - 1 - it) : it;

        // ---- A-frags: h^{it} from LDS (lane holds h[col][kc*32 + q*8 ..+8]) ----
        bf16x8 afr[16];
        #pragma unroll
        for (int kc = 0; kc < 16; ++kc)
            afr[kc] = *(const bf16x8*)&hlds[p][col][kc * 32 + q * 8];

        int mk[4];
        #pragma unroll
        for (int r = 0; r < 4; ++r) mk[r] = mask[(b0 + q * 4 + r) * T + t];

        // ---- z = h @ U : 16 k-chunks x 16 n-frags ----
        f32x4 acc[16];
        #pragma unroll
        for (int j = 0; j < 16; ++j) acc[j] = (f32x4){0.f, 0.f, 0.f, 0.f};
        #pragma unroll 2
        for (int kc = 0; kc < 16; ++kc) {
            bf16x8 bf[16];
            #pragma unroll
            for (int j = 0; j < 16; ++j)
                bf[j] = *(const bf16x8*)(bq[j] + boff + kc * 32);
            #pragma unroll
            for (int j = 0; j < 16; ++j)
                acc[j] = MFMA16(afr[kc], bf[j], acc[j]);
        }

        // ---- gates, state update, h -> LDS, y stores ----
        #pragma unroll
        for (int df = 0; df < 4; ++df) {
            const _Float16* xzp = xz + ((size_t)(t * 32 + w * 4 + df) * 64 + b0 + q * 4) * 64
                                  + col * 4;
            #pragma unroll
            for (int r = 0; r < 4; ++r) {
                f16x4 xzv = *(const f16x4*)(xzp + r * 64);
                float zi = acc[df][r]      + (float)xzv[0];
                float zf = acc[4 + df][r]  + (float)xzv[1];
                float zg = acc[8 + df][r]  + (float)xzv[2];
                float zo = acc[12 + df][r] + (float)xzv[3];
                float ig = sigmoidf_(zi);
                float fg = sigmoidf_(zf);
                float gg = tanhf_(zg);
                float og = sigmoidf_(zo);
                float cn = fg * creg[df][r] + ig * gg;
                float hn = og * tanhf_(cn);
                if (mk[r]) { creg[df][r] = cn; hreg[df][r] = hn; }
                u16 hb = f2bf(hreg[df][r]);
                hlds[p ^ 1][q * 4 + r][w * 64 + df * 16 + col] = hb;
                size_t ybase = ((size_t)(b0 + q * 4 + r) * T + t) * 1024 + dir * 512
                               + w * 64 + df * 16 + col;
                if (y_bf) __builtin_nontemporal_store(hb, y_bf + ybase);
                else      __builtin_nontemporal_store(hreg[df][r], y_f32 + ybase);
            }
        }
        __syncthreads();   // h^{it+1} fully in hlds[p^1]; reads of p done before writes of p next step
        p ^= 1;
    }

    if (hc_out) {
        #pragma unroll
        for (int df = 0; df < 4; ++df)
            #pragma unroll
            for (int r = 0; r < 4; ++r) {
                int b = b0 + q * 4 + r;
                int d = w * 64 + df * 16 + col;
                hc_out[(size_t)b * 1024 + dir * 512 + d] = hreg[df][r];
                hc_out[65536 + (size_t)b * 1024 + dir * 512 + d] = creg[df][r];
            }
    }
}

extern "C" void kernel_launch(void* const* d_in, const int* in_sizes, int n_in,
                              void* d_out, int out_size, void* d_ws, size_t ws_size,
                              hipStream_t stream) {
    const float* X   = (const float*)d_in[0];
    const float* Wf1 = (const float*)d_in[1];
    const float* Uf1 = (const float*)d_in[2];
    const float* bf1 = (const float*)d_in[3];
    const float* Wb1 = (const float*)d_in[4];
    const float* Ub1 = (const float*)d_in[5];
    const float* bb1 = (const float*)d_in[6];
    const float* Wf2 = (const float*)d_in[7];
    const float* Uf2 = (const float*)d_in[8];
    const float* bf2 = (const float*)d_in[9];
    const float* Wb2 = (const float*)d_in[10];
    const float* Ub2 = (const float*)d_in[11];
    const float* bb2 = (const float*)d_in[12];
    float* out = (float*)d_out;

    // scratch carved from d_out's H region (67.1 MB, dead until layer-2 rec):
    // y1bf 33.55 MB @0, Xbf 16.78 MB after; both consumed by layer-2 GEMMs (stream order).
    u16* y1bf = (u16*)d_out;
    u16* Xbf  = (u16*)((char*)d_out + 33554432);

    char* ws = (char*)d_ws;
    size_t off = 0;
    auto alloc = [&](size_t bytes) { char* p = ws + off; off = (off + bytes + 255) & ~(size_t)255; return p; };
    u16*  Wt1f  = (u16*)alloc(2048ull * 512 * 2);
    u16*  Wt1b  = (u16*)alloc(2048ull * 512 * 2);
    u16*  Wt2f  = (u16*)alloc(2048ull * 1024 * 2);
    u16*  Wt2b  = (u16*)alloc(2048ull * 1024 * 2);
    u16*  Ut1f  = (u16*)alloc(2048ull * 512 * 2);
    u16*  Ut1b  = (u16*)alloc(2048ull * 512 * 2);
    u16*  Ut2f  = (u16*)alloc(2048ull * 512 * 2);
    u16*  Ut2b  = (u16*)alloc(2048ull * 512 * 2);
    int*  maskb = (int*)alloc(16384ull * 4);
    _Float16* xzf = (_Float16*)alloc(16384ull * 2048 * 2);
    _Float16* xzb = (_Float16*)alloc(16384ull * 2048 * 2);
    (void)ws_size; (void)in_sizes; (void)n_in; (void)out_size;

    // prep
    mask_kernel<<<dim3(16384), dim3(64), 0, stream>>>(X, maskb);
    cast_bf16_kernel<<<dim3(8192), dim3(256), 0, stream>>>(X, Xbf, 16384 * 512);
    transpose_cast_kernel<<<dim3(64, 16), dim3(32, 8), 0, stream>>>(Wf1, Wt1f, 512, 2048);
    transpose_cast_kernel<<<dim3(64, 16), dim3(32, 8), 0, stream>>>(Wb1, Wt1b, 512, 2048);
    transpose_cast_kernel<<<dim3(64, 32), dim3(32, 8), 0, stream>>>(Wf2, Wt2f, 1024, 2048);
    transpose_cast_kernel<<<dim3(64, 32), dim3(32, 8), 0, stream>>>(Wb2, Wt2b, 1024, 2048);
    transpose_cast_kernel<<<dim3(64, 16), dim3(32, 8), 0, stream>>>(Uf1, Ut1f, 512, 2048);
    transpose_cast_kernel<<<dim3(64, 16), dim3(32, 8), 0, stream>>>(Ub1, Ut1b, 512, 2048);
    transpose_cast_kernel<<<dim3(64, 16), dim3(32, 8), 0, stream>>>(Uf2, Ut2f, 512, 2048);
    transpose_cast_kernel<<<dim3(64, 16), dim3(32, 8), 0, stream>>>(Ub2, Ut2b, 512, 2048);

    // layer 1
    gemm_xz_kernel<<<dim3(64, 16), dim3(256), 0, stream>>>(Xbf, Wt1f, bf1, xzf, 512);
    gemm_xz_kernel<<<dim3(64, 16), dim3(256), 0, stream>>>(Xbf, Wt1b, bb1, xzb, 512);
    lstm_rec13_kernel<<<dim3(4, 2), dim3(512), 0, stream>>>(
        xzf, xzb, Ut1f, Ut1b, maskb, y1bf, nullptr, nullptr);

    // layer 2
    gemm_xz_kernel<<<dim3(64, 16), dim3(256), 0, stream>>>(y1bf, Wt2f, bf2, xzf, 1024);
    gemm_xz_kernel<<<dim3(64, 16), dim3(256), 0, stream>>>(y1bf, Wt2b, bb2, xzb, 1024);
    lstm_rec13_kernel<<<dim3(4, 2), dim3(512), 0, stream>>>(
        xzf, xzb, Ut2f, Ut2b, maskb, nullptr, out, out + 16777216);
}

// Round 9
// 3797.775 us; speedup vs baseline: 9.5243x; 9.5243x over previous
//
#include <hip/hip_runtime.h>

typedef unsigned short u16;
typedef unsigned int u32;
typedef unsigned long long u64;
typedef __attribute__((ext_vector_type(8))) short bf16x8;
typedef __attribute__((ext_vector_type(4))) float f32x4;
typedef __attribute__((ext_vector_type(4))) _Float16 f16x4;

#define MFMA16(a, b, c) __builtin_amdgcn_mfma_f32_16x16x32_bf16((a), (b), (c), 0, 0, 0)

__device__ __forceinline__ u16 f2bf(float f) {
    union { float f; u32 u; } v; v.f = f;
    u32 r = v.u + 0x7FFFu + ((v.u >> 16) & 1u);
    return (u16)(r >> 16);
}
__device__ __forceinline__ float sigmoidf_(float x) {
    return 1.0f / (1.0f + __expf(-x));
}
__device__ __forceinline__ float tanhf_(float x) {
    float e = __expf(-2.0f * x);
    return (1.0f - e) / (1.0f + e);
}

// ---------------- fused mask + cast: one pass over X ----------------
// mask[row] = any(X[row,:512] != 0); out = bf16(X). Lane handles 8 contiguous
// elems (32 B load, 16 B store, both coalesced).
__global__ void mask_cast_kernel(const float* __restrict__ X, int* __restrict__ mask,
                                 u16* __restrict__ out) {
    int row = blockIdx.x;
    int lane = threadIdx.x;
    const float* r = X + (size_t)row * 512 + lane * 8;
    float4 v0 = *(const float4*)r;
    float4 v1 = *(const float4*)(r + 4);
    int nz = (v0.x != 0.f) | (v0.y != 0.f) | (v0.z != 0.f) | (v0.w != 0.f) |
             (v1.x != 0.f) | (v1.y != 0.f) | (v1.z != 0.f) | (v1.w != 0.f);
    nz = __any(nz);
    uint4 pk;
    pk.x = (u32)f2bf(v0.x) | ((u32)f2bf(v0.y) << 16);
    pk.y = (u32)f2bf(v0.z) | ((u32)f2bf(v0.w) << 16);
    pk.z = (u32)f2bf(v1.x) | ((u32)f2bf(v1.y) << 16);
    pk.w = (u32)f2bf(v1.z) | ((u32)f2bf(v1.w) << 16);
    *(uint4*)(out + (size_t)row * 512 + lane * 8) = pk;
    if (lane == 0) mask[row] = nz ? 1 : 0;
}

// ---------------- batched transpose + cast: in fp32 [K][N] -> out bf16 [N][K] -------
struct TBatch { const float* s[6]; u16* d[6]; };
__global__ void transpose_cast_batch_kernel(TBatch tb, int K, int N) {
    const float* __restrict__ in = tb.s[blockIdx.z];
    u16* __restrict__ out = tb.d[blockIdx.z];
    __shared__ float tile[32][33];
    int k0 = blockIdx.y * 32, n0 = blockIdx.x * 32;
    int tx = threadIdx.x, ty = threadIdx.y;
    #pragma unroll
    for (int i = ty; i < 32; i += 8)
        tile[i][tx] = in[(size_t)(k0 + i) * N + (n0 + tx)];
    __syncthreads();
    #pragma unroll
    for (int i = ty; i < 32; i += 8)
        out[(size_t)(n0 + i) * K + (k0 + tx)] = f2bf(tile[tx][i]);
}

// ---------------- GEMM: xz = A @ Bt^T + bias, both dirs in one dispatch ----------
// R18: grid (64, 32); dir = blockIdx.y>>4, sl = blockIdx.y&15. Co-resident blocks
// with equal blockIdx.x share A reads across dirs (A was previously re-pulled in
// full by the second dispatch). Body = R16 (4 m-frags x 8 n-frags, u64-contiguous
// epilogue). C element index: (((t*32 + slice)*64 + b)*16 + dcol)*4 + g,
// slice = sl*2 + half.
__global__ __launch_bounds__(256) void gemm_xz2_kernel(
        const u16* __restrict__ A,
        const u16* __restrict__ Btf, const u16* __restrict__ Btb,
        const float* __restrict__ biasf, const float* __restrict__ biasb,
        _Float16* __restrict__ Cf, _Float16* __restrict__ Cb, int K) {
    int w = threadIdx.x >> 6, lane = threadIdx.x & 63;
    int q = lane >> 4, col = lane & 15;
    int m0 = blockIdx.x * 256 + w * 64;   // wave's 64 rows (4 m-frags of 16)
    int dir = blockIdx.y >> 4;
    int sl = blockIdx.y & 15;             // double-slice 0..15 (dcols sl*32..+31)
    const u16* Bt = dir ? Btb : Btf;
    const float* bias = dir ? biasb : biasf;
    _Float16* C = dir ? Cb : Cf;

    const u16* arow = A + (size_t)(m0 + col) * K + q * 8;        // + mf*16*K
    const u16* brow = Bt + (size_t)(sl * 32 + col) * K + q * 8;  // + (half*16+g*512)*K

    f32x4 acc[4][8];   // [mf][half*4+g]
    #pragma unroll
    for (int mf = 0; mf < 4; ++mf)
        #pragma unroll
        for (int j = 0; j < 8; ++j) acc[mf][j] = (f32x4){0.f, 0.f, 0.f, 0.f};

    #pragma unroll 1
    for (int kc = 0; kc < K; kc += 32) {
        bf16x8 b[8], a[4];
        #pragma unroll
        for (int j = 0; j < 8; ++j) {
            int g = j & 3, half = j >> 2;
            b[j] = *(const bf16x8*)(brow + (size_t)(g * 512 + half * 16) * K + kc);
        }
        #pragma unroll
        for (int mf = 0; mf < 4; ++mf)
            a[mf] = *(const bf16x8*)(arow + (size_t)mf * 16 * K + kc);
        #pragma unroll
        for (int mf = 0; mf < 4; ++mf)
            #pragma unroll
            for (int j = 0; j < 8; ++j)
                acc[mf][j] = MFMA16(a[mf], b[j], acc[mf][j]);
    }

    float bs[8];
    #pragma unroll
    for (int j = 0; j < 8; ++j) {
        int g = j & 3, half = j >> 2;
        bs[j] = bias[g * 512 + sl * 32 + half * 16 + col];
    }

    #pragma unroll
    for (int mf = 0; mf < 4; ++mf) {
        #pragma unroll
        for (int r = 0; r < 4; ++r) {
            int row = m0 + mf * 16 + q * 4 + r;
            int b = row >> 8, t = row & 255;
            #pragma unroll
            for (int half = 0; half < 2; ++half) {
                union { _Float16 h[4]; u64 u; } pk;
                #pragma unroll
                for (int g = 0; g < 4; ++g)
                    pk.h[g] = (_Float16)(acc[mf][half * 4 + g][r] + bs[half * 4 + g]);
                size_t uidx = (((size_t)t * 32 + (sl * 2 + half)) * 64 + b) * 16 + col;
                ((u64*)C)[uidx] = pk.u;
            }
        }
    }
}

// ---------------- zero-init (flags) ----------------
__global__ void init_rec_kernel(u32* __restrict__ p, int n) {
    int i = blockIdx.x * 256 + threadIdx.x;
    if (i < n) p[i] = 0;
}

// ---------------- persistent d-sliced LSTM recurrence, v11: per-wave flags ---------
// (verbatim: round-3/5/6/7 kernel, 1535 us/dispatch; protocol frozen — rec9/10/12
//  exchange variants and rec13 batch-sliced all regressed.)
// grid (32 slices, 2 dirs) x 256 thr (4 waves). Block owns 16 h-dims x 4 gates.
//   (a) y stores after the flag publish; their HBM ACK drains during the next
//       step's poll wait, which is concurrent with waiting for producers.
//   (b) per-WAVE flags: exchange partitioned into 4 row-planes (producer wave w
//       writes rows 16w..16w+15; consumer wave w reads exactly those rows), so
//       each wave drains its own 2 WT stores and fires its own flag. No
//       __syncthreads in the loop.
// Safety (per plane w): flag_{w,s} >= k certifies wave w of block s published
//   h^k (vmcnt(0) drain precedes flag store) AND consumed slot (k-1)&1.
//   Step 0 consumes zero-registers, so hg needs no zero-init.
__global__ __launch_bounds__(256) void lstm_rec11_kernel(
        const _Float16* __restrict__ xz_f, const _Float16* __restrict__ xz_b,
        const u16* __restrict__ Ut_f, const u16* __restrict__ Ut_b,
        const int* __restrict__ mask,
        u32* __restrict__ flags,    // [dir*128 + wave*32 + slice] monotone counters
        u16* __restrict__ hg,       // [slot][dir][64][512] bf16, slot stride 65536
        u16* __restrict__ y_bf,     // layer1 out (null for layer2)
        float* __restrict__ y_f32,  // layer2 H out (null for layer1)
        float* __restrict__ hc_out) // layer2 hidden @0, cell @65536 (null for layer1)
{
    const int T = 256;
    int slice = blockIdx.x, dir = blockIdx.y;
    int tid = threadIdx.x;
    int lane = tid & 63, q = lane >> 4, col = lane & 15;
    int wv = tid >> 6;
    int ds = slice * 16, m0 = wv * 16;

    const _Float16* xz = dir ? xz_b : xz_f;
    const u16* Ut = dir ? Ut_b : Ut_f;
    u32* planeflags = flags + dir * 128 + wv * 32;   // this plane's 32 flags
    u32* myflag = planeflags + slice;

    // ---- stage U-slice into LDS once, per-fragment contiguous ----
    // cell = (g*16+kc)*64 + l; holds U[g*512+ds+(l&15)][kc*32+(l>>4)*8 ..+8].
    alignas(16) __shared__ u16 Ulds[4 * 16 * 64 * 8];  // 64 KB
    for (int cell = tid; cell < 4096; cell += 256) {
        int l = cell & 63, fr = cell >> 6;
        int kc = fr & 15, g = fr >> 4;
        *(uint4*)&Ulds[cell * 8] =
            *(const uint4*)(Ut + (size_t)(g * 512 + ds + (l & 15)) * 512 + kc * 32 + (l >> 4) * 8);
    }

    float creg[4] = {0.f, 0.f, 0.f, 0.f};
    float hreg[4] = {0.f, 0.f, 0.f, 0.f};
    __syncthreads();   // Ulds cross-wave staging only; no barriers inside the loop

    for (int it = 0; it < T; ++it) {
        int t = dir ? (T - 1 - it) : it;
        const u16* hsrc = hg + (it & 1) * 65536 + dir * 32768;
        u16* hdst = hg + ((it & 1) ^ 1) * 65536 + dir * 32768;

        // xz + mask loads for this step (independent of h) — issued before the poll
        f16x4 xzv[4];
        {
            const _Float16* xzt = xz + (((size_t)t * 32 + slice) * 64) * 64;
            #pragma unroll
            for (int r = 0; r < 4; ++r)
                xzv[r] = *(const f16x4*)(xzt + ((m0 + q * 4 + r) * 16 + col) * 4);
        }
        int mk[4];
        #pragma unroll
        for (int r = 0; r < 4; ++r) mk[r] = mask[(m0 + q * 4 + r) * T + t];

        // ---- poll this plane's 32 producer flags, then load h^{it} a-fragments ----
        bf16x8 afr[16];
        if (it == 0) {
            #pragma unroll
            for (int c = 0; c < 16; ++c)
                afr[c] = (bf16x8){0, 0, 0, 0, 0, 0, 0, 0};
        } else {
            u32 tgt = (u32)it;
            for (;;) {
                u32 f = __hip_atomic_load(planeflags + (lane & 31), __ATOMIC_RELAXED,
                                          __HIP_MEMORY_SCOPE_AGENT);
                if (__all(f >= tgt)) break;
                __builtin_amdgcn_s_sleep(1);
            }
            __builtin_amdgcn_sched_barrier(0);  // pin h loads after the poll
            const u64* hp = (const u64*)(hsrc + (size_t)(m0 + col) * 512 + q * 8);
            #pragma unroll
            for (int c = 0; c < 16; ++c) {
                union { u64 qw[2]; bf16x8 v; } u;
                u.qw[0] = __hip_atomic_load(hp + c * 8, __ATOMIC_RELAXED,
                                            __HIP_MEMORY_SCOPE_AGENT);
                u.qw[1] = __hip_atomic_load(hp + c * 8 + 1, __ATOMIC_RELAXED,
                                            __HIP_MEMORY_SCOPE_AGENT);
                afr[c] = u.v;
            }
        }

        // ---- z = h @ U for 4 gates x 16 dims x wave's 16 rows ----
        f32x4 acc[4];
        #pragma unroll
        for (int g = 0; g < 4; ++g) acc[g] = (f32x4){0.f, 0.f, 0.f, 0.f};
        #pragma unroll
        for (int kc = 0; kc < 16; ++kc) {
            #pragma unroll
            for (int g = 0; g < 4; ++g) {
                bf16x8 b = *(const bf16x8*)&Ulds[((g * 16 + kc) * 64 + lane) * 8];
                acc[g] = MFMA16(afr[kc], b, acc[g]);
            }
        }

        // ---- gates, state update ----
        u32 hbv[4];
        #pragma unroll
        for (int r = 0; r < 4; ++r) {
            float zi = acc[0][r] + (float)xzv[r][0];
            float zf = acc[1][r] + (float)xzv[r][1];
            float zg = acc[2][r] + (float)xzv[r][2];
            float zo = acc[3][r] + (float)xzv[r][3];
            float ig = sigmoidf_(zi);
            float fg = sigmoidf_(zf);
            float gg = tanhf_(zg);
            float og = sigmoidf_(zo);
            float cn = fg * creg[r] + ig * gg;
            float hn = og * tanhf_(cn);
            if (mk[r]) { creg[r] = cn; hreg[r] = hn; }
            hbv[r] = (u32)f2bf(hreg[r]);
        }

        // ---- publish h^{it+1}: pack dim pairs via shfl, WT u32 agent stores,
        //      per-wave drain, per-wave flag. Then y stores OFF the critical path.
        if (it < T - 1) {
            u32 part[4];
            #pragma unroll
            for (int r = 0; r < 4; ++r) part[r] = (u32)__shfl_xor((int)hbv[r], 1);
            int odd = col & 1;
            u32 p0 = odd ? (part[2] | (hbv[2] << 16)) : (hbv[0] | (part[0] << 16));
            u32 p1 = odd ? (part[3] | (hbv[3] << 16)) : (hbv[1] | (part[1] << 16));
            int r0 = q * 4 + (odd ? 2 : 0);
            u32* w0 = (u32*)(hdst + (size_t)(m0 + r0) * 512 + ds + (col & ~1));
            u32* w1 = (u32*)(hdst + (size_t)(m0 + r0 + 1) * 512 + ds + (col & ~1));
            __hip_atomic_store(w0, p0, __ATOMIC_RELAXED, __HIP_MEMORY_SCOPE_AGENT);
            __hip_atomic_store(w1, p1, __ATOMIC_RELAXED, __HIP_MEMORY_SCOPE_AGENT);
            // drain THIS WAVE's 2 WT stores (plus long-retired prev y stores)
            asm volatile("s_waitcnt vmcnt(0)" ::: "memory");
            if (lane == 0)
                __hip_atomic_store(myflag, (u32)(it + 1), __ATOMIC_RELAXED,
                                   __HIP_MEMORY_SCOPE_AGENT);
        }

        // ---- y stores after the publish (retire during next step's poll/compute) ----
        #pragma unroll
        for (int r = 0; r < 4; ++r) {
            int b = m0 + q * 4 + r;
            size_t ybase = ((size_t)b * T + t) * 1024 + dir * 512 + ds + col;
            if (y_bf) __builtin_nontemporal_store((u16)hbv[r], y_bf + ybase);
            else      __builtin_nontemporal_store(hreg[r], y_f32 + ybase);
        }
    }

    if (hc_out) {
        #pragma unroll
        for (int r = 0; r < 4; ++r) {
            int b = m0 + q * 4 + r;
            hc_out[(size_t)b * 1024 + dir * 512 + ds + col] = hreg[r];
            hc_out[65536 + (size_t)b * 1024 + dir * 512 + ds + col] = creg[r];
        }
    }
}

extern "C" void kernel_launch(void* const* d_in, const int* in_sizes, int n_in,
                              void* d_out, int out_size, void* d_ws, size_t ws_size,
                              hipStream_t stream) {
    const float* X   = (const float*)d_in[0];
    const float* Wf1 = (const float*)d_in[1];
    const float* Uf1 = (const float*)d_in[2];
    const float* bf1 = (const float*)d_in[3];
    const float* Wb1 = (const float*)d_in[4];
    const float* Ub1 = (const float*)d_in[5];
    const float* bb1 = (const float*)d_in[6];
    const float* Wf2 = (const float*)d_in[7];
    const float* Uf2 = (const float*)d_in[8];
    const float* bf2 = (const float*)d_in[9];
    const float* Wb2 = (const float*)d_in[10];
    const float* Ub2 = (const float*)d_in[11];
    const float* bb2 = (const float*)d_in[12];
    float* out = (float*)d_out;

    // scratch carved from d_out's H region (67.1 MB, dead until layer-2 rec):
    // y1bf 33.55 MB @0, Xbf 16.78 MB after; both consumed by layer-2 GEMMs (stream order).
    u16* y1bf = (u16*)d_out;
    u16* Xbf  = (u16*)((char*)d_out + 33554432);

    char* ws = (char*)d_ws;
    size_t off = 0;
    auto alloc = [&](size_t bytes) { char* p = ws + off; off = (off + bytes + 255) & ~(size_t)255; return p; };
    u16*  Wt1f  = (u16*)alloc(2048ull * 512 * 2);
    u16*  Wt1b  = (u16*)alloc(2048ull * 512 * 2);
    u16*  Wt2f  = (u16*)alloc(2048ull * 1024 * 2);
    u16*  Wt2b  = (u16*)alloc(2048ull * 1024 * 2);
    u16*  Ut1f  = (u16*)alloc(2048ull * 512 * 2);
    u16*  Ut1b  = (u16*)alloc(2048ull * 512 * 2);
    u16*  Ut2f  = (u16*)alloc(2048ull * 512 * 2);
    u16*  Ut2b  = (u16*)alloc(2048ull * 512 * 2);
    int*  maskb = (int*)alloc(16384ull * 4);
    // per-wave flags: 2 dirs x 4 waves x 32 slices = 256 u32 (1 KB)
    u32*  flags = (u32*)alloc(1024);
    // h exchange: 2 slots x 2 dirs x 64 x 512 bf16 = 256 KB (never read before
    // write: step 0 consumes zero registers, so no zero-init needed)
    u16*  hg    = (u16*)alloc(2ull * 2 * 64 * 512 * 2);
    _Float16* xzf = (_Float16*)alloc(16384ull * 2048 * 2);
    _Float16* xzb = (_Float16*)alloc(16384ull * 2048 * 2);
    (void)ws_size; (void)in_sizes; (void)n_in; (void)out_size;
    const int initN = 256;  // flag words only

    // prep: fused mask+cast (1 dispatch), batched transposes (2 dispatches)
    mask_cast_kernel<<<dim3(16384), dim3(64), 0, stream>>>(X, maskb, Xbf);
    TBatch tb6;
    tb6.s[0] = Wf1; tb6.d[0] = Wt1f;
    tb6.s[1] = Wb1; tb6.d[1] = Wt1b;
    tb6.s[2] = Uf1; tb6.d[2] = Ut1f;
    tb6.s[3] = Ub1; tb6.d[3] = Ut1b;
    tb6.s[4] = Uf2; tb6.d[4] = Ut2f;
    tb6.s[5] = Ub2; tb6.d[5] = Ut2b;
    transpose_cast_batch_kernel<<<dim3(64, 16, 6), dim3(32, 8), 0, stream>>>(tb6, 512, 2048);
    TBatch tb2;
    tb2.s[0] = Wf2; tb2.d[0] = Wt2f;
    tb2.s[1] = Wb2; tb2.d[1] = Wt2b;
    tb2.s[2] = nullptr; tb2.d[2] = nullptr;
    tb2.s[3] = nullptr; tb2.d[3] = nullptr;
    tb2.s[4] = nullptr; tb2.d[4] = nullptr;
    tb2.s[5] = nullptr; tb2.d[5] = nullptr;
    transpose_cast_batch_kernel<<<dim3(64, 32, 2), dim3(32, 8), 0, stream>>>(tb2, 1024, 2048);

    // layer 1 (both dirs in one GEMM dispatch)
    gemm_xz2_kernel<<<dim3(64, 32), dim3(256), 0, stream>>>(
        Xbf, Wt1f, Wt1b, bf1, bb1, xzf, xzb, 512);
    init_rec_kernel<<<dim3(1), dim3(256), 0, stream>>>(flags, initN);
    lstm_rec11_kernel<<<dim3(32, 2), dim3(256), 0, stream>>>(
        xzf, xzb, Ut1f, Ut1b, maskb, flags, hg, y1bf, nullptr, nullptr);

    // layer 2 (both dirs in one GEMM dispatch)
    gemm_xz2_kernel<<<dim3(64, 32), dim3(256), 0, stream>>>(
        y1bf, Wt2f, Wt2b, bf2, bb2, xzf, xzb, 1024);
    init_rec_kernel<<<dim3(1), dim3(256), 0, stream>>>(flags, initN);
    lstm_rec11_kernel<<<dim3(32, 2), dim3(256), 0, stream>>>(
        xzf, xzb, Ut2f, Ut2b, maskb, flags, hg, nullptr, out, out + 16777216);
}

// Round 10
// 2842.742 us; speedup vs baseline: 12.7240x; 1.3360x over previous
//
#include <hip/hip_runtime.h>

typedef unsigned short u16;
typedef unsigned int u32;
typedef unsigned long long u64;
typedef __attribute__((ext_vector_type(8))) short bf16x8;
typedef __attribute__((ext_vector_type(4))) float f32x4;
typedef __attribute__((ext_vector_type(4))) _Float16 f16x4;

#define MFMA16(a, b, c) __builtin_amdgcn_mfma_f32_16x16x32_bf16((a), (b), (c), 0, 0, 0)

__device__ __forceinline__ u16 f2bf(float f) {
    union { float f; u32 u; } v; v.f = f;
    u32 r = v.u + 0x7FFFu + ((v.u >> 16) & 1u);
    return (u16)(r >> 16);
}
__device__ __forceinline__ float sigmoidf_(float x) {
    return 1.0f / (1.0f + __expf(-x));
}
__device__ __forceinline__ float tanhf_(float x) {
    float e = __expf(-2.0f * x);
    return (1.0f - e) / (1.0f + e);
}

// ---------------- fused mask + cast: one pass over X ----------------
__global__ void mask_cast_kernel(const float* __restrict__ X, int* __restrict__ mask,
                                 u16* __restrict__ out) {
    int row = blockIdx.x;
    int lane = threadIdx.x;
    const float* r = X + (size_t)row * 512 + lane * 8;
    float4 v0 = *(const float4*)r;
    float4 v1 = *(const float4*)(r + 4);
    int nz = (v0.x != 0.f) | (v0.y != 0.f) | (v0.z != 0.f) | (v0.w != 0.f) |
             (v1.x != 0.f) | (v1.y != 0.f) | (v1.z != 0.f) | (v1.w != 0.f);
    nz = __any(nz);
    uint4 pk;
    pk.x = (u32)f2bf(v0.x) | ((u32)f2bf(v0.y) << 16);
    pk.y = (u32)f2bf(v0.z) | ((u32)f2bf(v0.w) << 16);
    pk.z = (u32)f2bf(v1.x) | ((u32)f2bf(v1.y) << 16);
    pk.w = (u32)f2bf(v1.z) | ((u32)f2bf(v1.w) << 16);
    *(uint4*)(out + (size_t)row * 512 + lane * 8) = pk;
    if (lane == 0) mask[row] = nz ? 1 : 0;
}

// ---------------- batched transpose + cast: in fp32 [K][N] -> out bf16 [N][K] -------
struct TBatch { const float* s[6]; u16* d[6]; };
__global__ void transpose_cast_batch_kernel(TBatch tb, int K, int N) {
    const float* __restrict__ in = tb.s[blockIdx.z];
    u16* __restrict__ out = tb.d[blockIdx.z];
    __shared__ float tile[32][33];
    int k0 = blockIdx.y * 32, n0 = blockIdx.x * 32;
    int tx = threadIdx.x, ty = threadIdx.y;
    #pragma unroll
    for (int i = ty; i < 32; i += 8)
        tile[i][tx] = in[(size_t)(k0 + i) * N + (n0 + tx)];
    __syncthreads();
    #pragma unroll
    for (int i = ty; i < 32; i += 8)
        out[(size_t)(n0 + i) * K + (k0 + tx)] = f2bf(tile[tx][i]);
}

// ---------------- GEMM: xz = A @ Bt^T + bias, both dirs in one dispatch (R18) -------
// C element index: (((t*32 + slice)*64 + b)*16 + dcol)*4 + g, slice = sl*2 + half.
__global__ __launch_bounds__(256) void gemm_xz2_kernel(
        const u16* __restrict__ A,
        const u16* __restrict__ Btf, const u16* __restrict__ Btb,
        const float* __restrict__ biasf, const float* __restrict__ biasb,
        _Float16* __restrict__ Cf, _Float16* __restrict__ Cb, int K) {
    int w = threadIdx.x >> 6, lane = threadIdx.x & 63;
    int q = lane >> 4, col = lane & 15;
    int m0 = blockIdx.x * 256 + w * 64;   // wave's 64 rows (4 m-frags of 16)
    int dir = blockIdx.y >> 4;
    int sl = blockIdx.y & 15;             // double-slice 0..15 (dcols sl*32..+31)
    const u16* Bt = dir ? Btb : Btf;
    const float* bias = dir ? biasb : biasf;
    _Float16* C = dir ? Cb : Cf;

    const u16* arow = A + (size_t)(m0 + col) * K + q * 8;        // + mf*16*K
    const u16* brow = Bt + (size_t)(sl * 32 + col) * K + q * 8;  // + (half*16+g*512)*K

    f32x4 acc[4][8];   // [mf][half*4+g]
    #pragma unroll
    for (int mf = 0; mf < 4; ++mf)
        #pragma unroll
        for (int j = 0; j < 8; ++j) acc[mf][j] = (f32x4){0.f, 0.f, 0.f, 0.f};

    #pragma unroll 1
    for (int kc = 0; kc < K; kc += 32) {
        bf16x8 b[8], a[4];
        #pragma unroll
        for (int j = 0; j < 8; ++j) {
            int g = j & 3, half = j >> 2;
            b[j] = *(const bf16x8*)(brow + (size_t)(g * 512 + half * 16) * K + kc);
        }
        #pragma unroll
        for (int mf = 0; mf < 4; ++mf)
            a[mf] = *(const bf16x8*)(arow + (size_t)mf * 16 * K + kc);
        #pragma unroll
        for (int mf = 0; mf < 4; ++mf)
            #pragma unroll
            for (int j = 0; j < 8; ++j)
                acc[mf][j] = MFMA16(a[mf], b[j], acc[mf][j]);
    }

    float bs[8];
    #pragma unroll
    for (int j = 0; j < 8; ++j) {
        int g = j & 3, half = j >> 2;
        bs[j] = bias[g * 512 + sl * 32 + half * 16 + col];
    }

    #pragma unroll
    for (int mf = 0; mf < 4; ++mf) {
        #pragma unroll
        for (int r = 0; r < 4; ++r) {
            int row = m0 + mf * 16 + q * 4 + r;
            int b = row >> 8, t = row & 255;
            #pragma unroll
            for (int half = 0; half < 2; ++half) {
                union { _Float16 h[4]; u64 u; } pk;
                #pragma unroll
                for (int g = 0; g < 4; ++g)
                    pk.h[g] = (_Float16)(acc[mf][half * 4 + g][r] + bs[half * 4 + g]);
                size_t uidx = (((size_t)t * 32 + (sl * 2 + half)) * 64 + b) * 16 + col;
                ((u64*)C)[uidx] = pk.u;
            }
        }
    }
}

// ---------------- zero-init (flags) ----------------
__global__ void init_rec_kernel(u32* __restrict__ p, int n) {
    int i = blockIdx.x * 256 + threadIdx.x;
    if (i < n) p[i] = 0;
}

// ---------------- persistent d-sliced LSTM recurrence, v14: exclusive-line layout --
// R19 vs rec11 (protocol & instruction types byte-identical; PURE address remap):
//  (a) hg reordered [slot][dir][slice][row][16]: each (block,wave)'s publish is a
//      contiguous 512-B region with a SINGLE writer. Old [row][512] layout had
//      every 64-B line written by 2 different blocks per step (line ping-pong at
//      the coherence point breaks write-combining).
//  (b) flags padded to one 64-B line per producer (flags[... + slice*16]): old
//      layout had 32 producers storing into one 128-B region each step; the
//      __all() poll waits on the LAST flag, which pays the line-serialization.
// Consumer a-frag read: lane needs dims kc*32+q*8..+8 of row m0+col ->
//   chunk 2kc+(q>>1), offset (q&1)*8: hq[kc*512 + (q>>1)*256 + myrow*4 + (q&1)*2].
// Safety (per plane w, unchanged): flag_{w,s} >= k certifies wave w of block s
//   published h^k (vmcnt(0) drain precedes flag store) AND consumed slot (k-1)&1.
//   Step 0 consumes zero-registers, so hg needs no zero-init.
__global__ __launch_bounds__(256) void lstm_rec14_kernel(
        const _Float16* __restrict__ xz_f, const _Float16* __restrict__ xz_b,
        const u16* __restrict__ Ut_f, const u16* __restrict__ Ut_b,
        const int* __restrict__ mask,
        u32* __restrict__ flags,    // [(dir*128 + wave*32 + slice) * 16] padded lines
        u16* __restrict__ hg,       // [slot][dir][slice][64][16] bf16, slot stride 65536
        u16* __restrict__ y_bf,     // layer1 out (null for layer2)
        float* __restrict__ y_f32,  // layer2 H out (null for layer1)
        float* __restrict__ hc_out) // layer2 hidden @0, cell @65536 (null for layer1)
{
    const int T = 256;
    int slice = blockIdx.x, dir = blockIdx.y;
    int tid = threadIdx.x;
    int lane = tid & 63, q = lane >> 4, col = lane & 15;
    int wv = tid >> 6;
    int ds = slice * 16, m0 = wv * 16;

    const _Float16* xz = dir ? xz_b : xz_f;
    const u16* Ut = dir ? Ut_b : Ut_f;
    u32* planeflags = flags + (dir * 128 + wv * 32) * 16;   // 16 u32 (64 B) per flag
    u32* myflag = planeflags + slice * 16;

    // ---- stage U-slice into LDS once, per-fragment contiguous ----
    // cell = (g*16+kc)*64 + l; holds U[g*512+ds+(l&15)][kc*32+(l>>4)*8 ..+8].
    alignas(16) __shared__ u16 Ulds[4 * 16 * 64 * 8];  // 64 KB
    for (int cell = tid; cell < 4096; cell += 256) {
        int l = cell & 63, fr = cell >> 6;
        int kc = fr & 15, g = fr >> 4;
        *(uint4*)&Ulds[cell * 8] =
            *(const uint4*)(Ut + (size_t)(g * 512 + ds + (l & 15)) * 512 + kc * 32 + (l >> 4) * 8);
    }

    // consumer base (u64 units): myrow*4 + (q&1)*2 + (q>>1)*256; + kc*512 per chunk-pair
    int myrow = m0 + col;
    int cbase = myrow * 4 + (q & 1) * 2 + (q >> 1) * 256;
    // producer: row r0 block (own 64-B lines within [slice][row][16])
    int odd = col & 1;
    int r0 = q * 4 + (odd ? 2 : 0);
    size_t pbase = ((size_t)slice * 64 + m0 + r0) * 16 + (col & ~1);

    float creg[4] = {0.f, 0.f, 0.f, 0.f};
    float hreg[4] = {0.f, 0.f, 0.f, 0.f};
    __syncthreads();   // Ulds cross-wave staging only; no barriers inside the loop

    for (int it = 0; it < T; ++it) {
        int t = dir ? (T - 1 - it) : it;
        const u64* hq = (const u64*)(hg + (it & 1) * 65536 + dir * 32768);
        u16* hdst = hg + ((it & 1) ^ 1) * 65536 + dir * 32768;

        // xz + mask loads for this step (independent of h) — issued before the poll
        f16x4 xzv[4];
        {
            const _Float16* xzt = xz + (((size_t)t * 32 + slice) * 64) * 64;
            #pragma unroll
            for (int r = 0; r < 4; ++r)
                xzv[r] = *(const f16x4*)(xzt + ((m0 + q * 4 + r) * 16 + col) * 4);
        }
        int mk[4];
        #pragma unroll
        for (int r = 0; r < 4; ++r) mk[r] = mask[(m0 + q * 4 + r) * T + t];

        // ---- poll this plane's 32 producer flags (one line each), then load h ----
        bf16x8 afr[16];
        if (it == 0) {
            #pragma unroll
            for (int c = 0; c < 16; ++c)
                afr[c] = (bf16x8){0, 0, 0, 0, 0, 0, 0, 0};
        } else {
            u32 tgt = (u32)it;
            for (;;) {
                u32 f = __hip_atomic_load(planeflags + (lane & 31) * 16,
                                          __ATOMIC_RELAXED, __HIP_MEMORY_SCOPE_AGENT);
                if (__all(f >= tgt)) break;
                __builtin_amdgcn_s_sleep(1);
            }
            __builtin_amdgcn_sched_barrier(0);  // pin h loads after the poll
            #pragma unroll
            for (int c = 0; c < 16; ++c) {
                union { u64 qw[2]; bf16x8 v; } u;
                u.qw[0] = __hip_atomic_load(hq + c * 512 + cbase, __ATOMIC_RELAXED,
                                            __HIP_MEMORY_SCOPE_AGENT);
                u.qw[1] = __hip_atomic_load(hq + c * 512 + cbase + 1, __ATOMIC_RELAXED,
                                            __HIP_MEMORY_SCOPE_AGENT);
                afr[c] = u.v;
            }
        }

        // ---- z = h @ U for 4 gates x 16 dims x wave's 16 rows ----
        f32x4 acc[4];
        #pragma unroll
        for (int g = 0; g < 4; ++g) acc[g] = (f32x4){0.f, 0.f, 0.f, 0.f};
        #pragma unroll
        for (int kc = 0; kc < 16; ++kc) {
            #pragma unroll
            for (int g = 0; g < 4; ++g) {
                bf16x8 b = *(const bf16x8*)&Ulds[((g * 16 + kc) * 64 + lane) * 8];
                acc[g] = MFMA16(afr[kc], b, acc[g]);
            }
        }

        // ---- gates, state update ----
        u32 hbv[4];
        #pragma unroll
        for (int r = 0; r < 4; ++r) {
            float zi = acc[0][r] + (float)xzv[r][0];
            float zf = acc[1][r] + (float)xzv[r][1];
            float zg = acc[2][r] + (float)xzv[r][2];
            float zo = acc[3][r] + (float)xzv[r][3];
            float ig = sigmoidf_(zi);
            float fg = sigmoidf_(zf);
            float gg = tanhf_(zg);
            float og = sigmoidf_(zo);
            float cn = fg * creg[r] + ig * gg;
            float hn = og * tanhf_(cn);
            if (mk[r]) { creg[r] = cn; hreg[r] = hn; }
            hbv[r] = (u32)f2bf(hreg[r]);
        }

        // ---- publish h^{it+1}: pack dim pairs via shfl, WT u32 agent stores into
        //      the wave's EXCLUSIVE lines, per-wave drain, per-wave padded flag.
        if (it < T - 1) {
            u32 part[4];
            #pragma unroll
            for (int r = 0; r < 4; ++r) part[r] = (u32)__shfl_xor((int)hbv[r], 1);
            u32 p0 = odd ? (part[2] | (hbv[2] << 16)) : (hbv[0] | (part[0] << 16));
            u32 p1 = odd ? (part[3] | (hbv[3] << 16)) : (hbv[1] | (part[1] << 16));
            u32* w0 = (u32*)(hdst + pbase);
            u32* w1 = w0 + 8;   // next row: +16 u16 = +8 u32
            __hip_atomic_store(w0, p0, __ATOMIC_RELAXED, __HIP_MEMORY_SCOPE_AGENT);
            __hip_atomic_store(w1, p1, __ATOMIC_RELAXED, __HIP_MEMORY_SCOPE_AGENT);
            // drain THIS WAVE's 2 WT stores (plus long-retired prev y stores)
            asm volatile("s_waitcnt vmcnt(0)" ::: "memory");
            if (lane == 0)
                __hip_atomic_store(myflag, (u32)(it + 1), __ATOMIC_RELAXED,
                                   __HIP_MEMORY_SCOPE_AGENT);
        }

        // ---- y stores after the publish (retire during next step's poll/compute) ----
        #pragma unroll
        for (int r = 0; r < 4; ++r) {
            int b = m0 + q * 4 + r;
            size_t ybase = ((size_t)b * T + t) * 1024 + dir * 512 + ds + col;
            if (y_bf) __builtin_nontemporal_store((u16)hbv[r], y_bf + ybase);
            else      __builtin_nontemporal_store(hreg[r], y_f32 + ybase);
        }
    }

    if (hc_out) {
        #pragma unroll
        for (int r = 0; r < 4; ++r) {
            int b = m0 + q * 4 + r;
            hc_out[(size_t)b * 1024 + dir * 512 + ds + col] = hreg[r];
            hc_out[65536 + (size_t)b * 1024 + dir * 512 + ds + col] = creg[r];
        }
    }
}

extern "C" void kernel_launch(void* const* d_in, const int* in_sizes, int n_in,
                              void* d_out, int out_size, void* d_ws, size_t ws_size,
                              hipStream_t stream) {
    const float* X   = (const float*)d_in[0];
    const float* Wf1 = (const float*)d_in[1];
    const float* Uf1 = (const float*)d_in[2];
    const float* bf1 = (const float*)d_in[3];
    const float* Wb1 = (const float*)d_in[4];
    const float* Ub1 = (const float*)d_in[5];
    const float* bb1 = (const float*)d_in[6];
    const float* Wf2 = (const float*)d_in[7];
    const float* Uf2 = (const float*)d_in[8];
    const float* bf2 = (const float*)d_in[9];
    const float* Wb2 = (const float*)d_in[10];
    const float* Ub2 = (const float*)d_in[11];
    const float* bb2 = (const float*)d_in[12];
    float* out = (float*)d_out;

    // scratch carved from d_out's H region (67.1 MB, dead until layer-2 rec):
    // y1bf 33.55 MB @0, Xbf 16.78 MB after; both consumed by layer-2 GEMMs (stream order).
    u16* y1bf = (u16*)d_out;
    u16* Xbf  = (u16*)((char*)d_out + 33554432);

    char* ws = (char*)d_ws;
    size_t off = 0;
    auto alloc = [&](size_t bytes) { char* p = ws + off; off = (off + bytes + 255) & ~(size_t)255; return p; };
    u16*  Wt1f  = (u16*)alloc(2048ull * 512 * 2);
    u16*  Wt1b  = (u16*)alloc(2048ull * 512 * 2);
    u16*  Wt2f  = (u16*)alloc(2048ull * 1024 * 2);
    u16*  Wt2b  = (u16*)alloc(2048ull * 1024 * 2);
    u16*  Ut1f  = (u16*)alloc(2048ull * 512 * 2);
    u16*  Ut1b  = (u16*)alloc(2048ull * 512 * 2);
    u16*  Ut2f  = (u16*)alloc(2048ull * 512 * 2);
    u16*  Ut2b  = (u16*)alloc(2048ull * 512 * 2);
    int*  maskb = (int*)alloc(16384ull * 4);
    // padded flags: 2 dirs x 4 waves x 32 slices x 16 u32 (64 B/line) = 16 KB
    u32*  flags = (u32*)alloc(16384);
    // h exchange: [slot][dir][slice][64][16] = 2*2*32*64*16 u16 = 256 KB
    // (never read before write: step 0 consumes zero registers, no zero-init)
    u16*  hg    = (u16*)alloc(2ull * 2 * 32 * 64 * 16 * 2);
    _Float16* xzf = (_Float16*)alloc(16384ull * 2048 * 2);
    _Float16* xzb = (_Float16*)alloc(16384ull * 2048 * 2);
    (void)ws_size; (void)in_sizes; (void)n_in; (void)out_size;
    const int initN = 4096;  // padded flag words

    // prep: fused mask+cast (1 dispatch), batched transposes (2 dispatches)
    mask_cast_kernel<<<dim3(16384), dim3(64), 0, stream>>>(X, maskb, Xbf);
    TBatch tb6;
    tb6.s[0] = Wf1; tb6.d[0] = Wt1f;
    tb6.s[1] = Wb1; tb6.d[1] = Wt1b;
    tb6.s[2] = Uf1; tb6.d[2] = Ut1f;
    tb6.s[3] = Ub1; tb6.d[3] = Ut1b;
    tb6.s[4] = Uf2; tb6.d[4] = Ut2f;
    tb6.s[5] = Ub2; tb6.d[5] = Ut2b;
    transpose_cast_batch_kernel<<<dim3(64, 16, 6), dim3(32, 8), 0, stream>>>(tb6, 512, 2048);
    TBatch tb2;
    tb2.s[0] = Wf2; tb2.d[0] = Wt2f;
    tb2.s[1] = Wb2; tb2.d[1] = Wt2b;
    tb2.s[2] = nullptr; tb2.d[2] = nullptr;
    tb2.s[3] = nullptr; tb2.d[3] = nullptr;
    tb2.s[4] = nullptr; tb2.d[4] = nullptr;
    tb2.s[5] = nullptr; tb2.d[5] = nullptr;
    transpose_cast_batch_kernel<<<dim3(64, 32, 2), dim3(32, 8), 0, stream>>>(tb2, 1024, 2048);

    // layer 1 (both dirs in one GEMM dispatch)
    gemm_xz2_kernel<<<dim3(64, 32), dim3(256), 0, stream>>>(
        Xbf, Wt1f, Wt1b, bf1, bb1, xzf, xzb, 512);
    init_rec_kernel<<<dim3(16), dim3(256), 0, stream>>>(flags, initN);
    lstm_rec14_kernel<<<dim3(32, 2), dim3(256), 0, stream>>>(
        xzf, xzb, Ut1f, Ut1b, maskb, flags, hg, y1bf, nullptr, nullptr);

    // layer 2 (both dirs in one GEMM dispatch)
    gemm_xz2_kernel<<<dim3(64, 32), dim3(256), 0, stream>>>(
        y1bf, Wt2f, Wt2b, bf2, bb2, xzf, xzb, 1024);
    init_rec_kernel<<<dim3(16), dim3(256), 0, stream>>>(flags, initN);
    lstm_rec14_kernel<<<dim3(32, 2), dim3(256), 0, stream>>>(
        xzf, xzb, Ut2f, Ut2b, maskb, flags, hg, nullptr, out, out + 16777216);
}